// Round 10
// baseline (725.715 us; speedup 1.0000x reference)
//
#include <hip/hip_runtime.h>

#define B_     8
#define N_     16384
#define F_     64
#define E_     262144
#define C_     10
#define NF_    (N_ * F_)        // 1048576
#define BN_    (B_ * N_)        // 131072
#define BNF_   (B_ * N_ * F_)   // 8388608
#define BE_    (B_ * E_)        // 2097152
#define CAP_   48               // padded CSR row capacity; P(Poisson(16) >= 48) ~ 6e-11
#define CHUNK_ 4096             // edges per build workgroup
#define NCH_   (E_ / CHUNK_)    // 64 chunks per batch
#define NW_    (N_ / 4)         // 4096 packed-u8 words per batch
#define NBLK_  (BN_ / 16)       // 8192 gather blocks (stats partials rows)
#define EPS_   1e-5f

// ---------------- Build phase A: per-chunk privatized counts ----------------
__global__ __launch_bounds__(256) void k_count(const int* __restrict__ src,
                                               const int* __restrict__ dst,
                                               unsigned int* __restrict__ partO,
                                               unsigned int* __restrict__ partI) {
    __shared__ unsigned int pO[NW_];  // 16 KB
    __shared__ unsigned int pI[NW_];  // 16 KB
    int t = threadIdx.x;
    int b = blockIdx.x & 7, c = blockIdx.x >> 3;
    for (int i = t; i < NW_; i += 256) { pO[i] = 0; pI[i] = 0; }
    __syncthreads();
    const int* sb = src + (size_t)b * E_ + (size_t)c * CHUNK_;
    const int* db = dst + (size_t)b * E_ + (size_t)c * CHUNK_;
    for (int i = t; i < CHUNK_; i += 256) {
        int s = sb[i], d = db[i];
        atomicAdd(&pO[s >> 2], 1u << ((s & 3) * 8));
        atomicAdd(&pI[d >> 2], 1u << ((d & 3) * 8));
    }
    __syncthreads();
    size_t base = (size_t)(b * NCH_ + c) * NW_;
    for (int i = t; i < NW_; i += 256) {
        partO[base + i] = pO[i];
        partI[base + i] = pI[i];
    }
}

// ---------------- Build phase B: packed prefix over chunks + degrees --------
__global__ __launch_bounds__(256) void k_offsets(const unsigned int* __restrict__ partO,
                                                 const unsigned int* __restrict__ partI,
                                                 unsigned int* __restrict__ baseArr,
                                                 float* __restrict__ degOr,
                                                 float* __restrict__ degIr,
                                                 int* __restrict__ cntI_g) {
    int gw = blockIdx.x * 256 + threadIdx.x;  // word id in [0, BN_/4)
    int b = gw >> 12;
    int rw = gw & 4095;
    unsigned int sumI = 0, sumO = 0;
    for (int c = 0; c < NCH_; ++c) {
        size_t idx = (size_t)(b * NCH_ + c) * NW_ + rw;
        unsigned int wI = partI[idx];
        baseArr[idx] = sumI;  // exclusive prefix, packed u8 lanes
        sumI += wI;
        sumO += partO[idx];
    }
    int row0 = gw * 4;
#pragma unroll
    for (int r = 0; r < 4; ++r) {
        unsigned int ci = (sumI >> (r * 8)) & 0xFFu;
        unsigned int co = (sumO >> (r * 8)) & 0xFFu;
        degIr[row0 + r] = rsqrtf(fmaxf((float)ci, 1.0f));
        degOr[row0 + r] = rsqrtf(fmaxf((float)co, 1.0f));
        cntI_g[row0 + r] = (int)ci;
    }
}

// ---------------- Build phase C: deterministic-offset CSR fill --------------
__global__ __launch_bounds__(256) void k_fill(const int* __restrict__ src,
                                              const int* __restrict__ dst,
                                              const unsigned int* __restrict__ baseArr,
                                              unsigned short* __restrict__ csr) {
    __shared__ unsigned int cur[NW_];  // 16 KB
    __shared__ unsigned int bw[NW_];   // 16 KB
    int t = threadIdx.x;
    int b = blockIdx.x & 7, c = blockIdx.x >> 3;
    size_t pbase = (size_t)(b * NCH_ + c) * NW_;
    for (int i = t; i < NW_; i += 256) { cur[i] = 0; bw[i] = baseArr[pbase + i]; }
    __syncthreads();
    const int* sb = src + (size_t)b * E_ + (size_t)c * CHUNK_;
    const int* db = dst + (size_t)b * E_ + (size_t)c * CHUNK_;
    unsigned short* cb = csr + (size_t)b * N_ * CAP_;
    for (int i = t; i < CHUNK_; i += 256) {
        int s = sb[i], d = db[i];
        unsigned int sh = (d & 3) * 8;
        unsigned int old = atomicAdd(&cur[d >> 2], 1u << sh);
        unsigned int pos = ((old >> sh) & 0xFFu) + ((bw[d >> 2] >> sh) & 0xFFu);
        if (pos < CAP_) cb[d * CAP_ + pos] = (unsigned short)s;
    }
}

// ---------------- Dense mm: out = (in @ W) [* rowScale] ---------------------
template <bool SCALE>
__global__ __launch_bounds__(256) void k_mmd(const float* __restrict__ in,
                                             const float* __restrict__ W,
                                             const float* __restrict__ rs,
                                             float* __restrict__ out) {
    __shared__ float Wl[4096];        // 16 KB
    __shared__ float4 rows[16][16];   // 4 KB  [row][kGroup]
    int t = threadIdx.x;
    int b = blockIdx.x & 7;
    int rowg = b * N_ + (blockIdx.x >> 3) * 16;  // global row base
    for (int i = t; i < 1024; i += 256) ((float4*)Wl)[i] = ((const float4*)W)[i];
    rows[t >> 4][t & 15] = ((const float4*)(in + (size_t)(rowg + (t >> 4)) * 64))[t & 15];
    __syncthreads();
    int f = t & 63;
    int wv = t >> 6;  // wave -> rows wv*4 .. wv*4+3
    float a0 = 0.0f, a1 = 0.0f, a2 = 0.0f, a3 = 0.0f;
#pragma unroll
    for (int kg = 0; kg < 16; ++kg) {
        float4 r0 = rows[wv * 4 + 0][kg];
        float4 r1 = rows[wv * 4 + 1][kg];
        float4 r2 = rows[wv * 4 + 2][kg];
        float4 r3 = rows[wv * 4 + 3][kg];
        float w0 = Wl[(kg * 4 + 0) * 64 + f];
        float w1 = Wl[(kg * 4 + 1) * 64 + f];
        float w2 = Wl[(kg * 4 + 2) * 64 + f];
        float w3 = Wl[(kg * 4 + 3) * 64 + f];
        a0 = fmaf(r0.x, w0, a0); a0 = fmaf(r0.y, w1, a0); a0 = fmaf(r0.z, w2, a0); a0 = fmaf(r0.w, w3, a0);
        a1 = fmaf(r1.x, w0, a1); a1 = fmaf(r1.y, w1, a1); a1 = fmaf(r1.z, w2, a1); a1 = fmaf(r1.w, w3, a1);
        a2 = fmaf(r2.x, w0, a2); a2 = fmaf(r2.y, w1, a2); a2 = fmaf(r2.z, w2, a2); a2 = fmaf(r2.w, w3, a2);
        a3 = fmaf(r3.x, w0, a3); a3 = fmaf(r3.y, w1, a3); a3 = fmaf(r3.z, w2, a3); a3 = fmaf(r3.w, w3, a3);
    }
    int r0i = rowg + wv * 4;
    if (SCALE) {
        a0 *= rs[r0i]; a1 *= rs[r0i + 1]; a2 *= rs[r0i + 2]; a3 *= rs[r0i + 3];
    }
    out[(size_t)(r0i + 0) * 64 + f] = a0;
    out[(size_t)(r0i + 1) * 64 + f] = a1;
    out[(size_t)(r0i + 2) * 64 + f] = a2;
    out[(size_t)(r0i + 3) * 64 + f] = a3;
}

// ---------------- Lean gather + epilogue [+ fused BN stats partials] --------
// 256 threads = 4 waves; wave handles 4 rows. Lane: r = lane>>4, c = lane&15.
// CONV1: out = relu(g*degIr + b1) * degOr     CONV2: out = g*degIr + b2
// STATS: per-block channel sum/sumsq -> partials[block][128] (coalesced).
template <bool CONV1, bool STATS>
__global__ __launch_bounds__(256, 8) void k_gat(
        const int* __restrict__ cnt, const unsigned short* __restrict__ csr,
        const float* __restrict__ z, const float* __restrict__ degIr,
        const float* __restrict__ degOr, const float* __restrict__ bias,
        float* __restrict__ out, float* __restrict__ statPart) {
    __shared__ float ssum[64], ssq[64];
    int t = threadIdx.x;
    if (STATS) {
        if (t < 64) { ssum[t] = 0.0f; ssq[t] = 0.0f; }
        __syncthreads();
    }
    int lane = t & 63;
    int wave = t >> 6;
    int c = lane & 15;
    int b = blockIdx.x & 7;  // XCD swizzle: batch slice L2-resident
    int row = (blockIdx.x >> 3) * 16 + wave * 4 + (lane >> 4);
    int wid = b * N_ + row;
    const float* zb = z + (size_t)b * NF_;
    int lb = lane & 48;
    int co = c * 4;

    int n = cnt[wid];
    if (n > CAP_) n = CAP_;
    size_t cb = (size_t)wid * CAP_;
    int e0 = csr[cb + c] & 0x3FFF;        // mask: entries >= n may be stale
    int e1 = csr[cb + 16 + c] & 0x3FFF;
    int e2 = csr[cb + 32 + c] & 0x3FFF;
    float dIr = degIr[wid];               // early loads overlap gather
    const float4 bv = ((const float4*)bias)[c];
    int m = n;  // wave-uniform max count across the 4 rows
    m = max(m, __shfl_xor(m, 16));
    m = max(m, __shfl_xor(m, 32));

    float ax = 0.0f, ay = 0.0f, az = 0.0f, aw = 0.0f;

#define HALF(EREG, KOFF, JBASE)                                                \
    {                                                                          \
        float4 v[8];                                                           \
        int rem = n - (KOFF);                                                  \
        _Pragma("unroll")                                                      \
        for (int jj = 0; jj < 8; ++jj) {                                       \
            int s = __shfl(EREG, lb + (JBASE) + jj);                           \
            v[jj] = make_float4(0.0f, 0.0f, 0.0f, 0.0f);                       \
            if (jj < rem) v[jj] = *(const float4*)(zb + s * 64 + co);          \
        }                                                                      \
        _Pragma("unroll")                                                      \
        for (int jj = 0; jj < 8; ++jj) {                                       \
            ax += v[jj].x; ay += v[jj].y; az += v[jj].z; aw += v[jj].w;        \
        }                                                                      \
    }

    HALF(e0, 0, 0)
    if (m > 8)  HALF(e0, 8, 8)
    if (m > 16) HALF(e1, 16, 0)
    if (m > 24) HALF(e1, 24, 8)
    if (m > 32) HALF(e2, 32, 0)
    if (m > 40) HALF(e2, 40, 8)
#undef HALF

    float ox, oy, oz, ow;
    if (CONV1) {
        float po = degOr[wid];
        ox = fmaxf(fmaf(ax, dIr, bv.x), 0.0f) * po;
        oy = fmaxf(fmaf(ay, dIr, bv.y), 0.0f) * po;
        oz = fmaxf(fmaf(az, dIr, bv.z), 0.0f) * po;
        ow = fmaxf(fmaf(aw, dIr, bv.w), 0.0f) * po;
    } else {
        ox = fmaf(ax, dIr, bv.x);
        oy = fmaf(ay, dIr, bv.y);
        oz = fmaf(az, dIr, bv.z);
        ow = fmaf(aw, dIr, bv.w);
    }
    float4 o; o.x = ox; o.y = oy; o.z = oz; o.w = ow;
    *(float4*)(out + (size_t)wid * 64 + co) = o;

    if (STATS) {
        float sx = ox * ox, sy = oy * oy, sz = oz * oz, sw = ow * ow;
        // sum over the wave's 4 rows (lanes l, l^16, l^32, l^48)
        float rx = ox + __shfl_xor(ox, 16); rx += __shfl_xor(rx, 32);
        float ry = oy + __shfl_xor(oy, 16); ry += __shfl_xor(ry, 32);
        float rz = oz + __shfl_xor(oz, 16); rz += __shfl_xor(rz, 32);
        float rw2 = ow + __shfl_xor(ow, 16); rw2 += __shfl_xor(rw2, 32);
        float qx = sx + __shfl_xor(sx, 16); qx += __shfl_xor(qx, 32);
        float qy = sy + __shfl_xor(sy, 16); qy += __shfl_xor(qy, 32);
        float qz = sz + __shfl_xor(sz, 16); qz += __shfl_xor(qz, 32);
        float qw = sw + __shfl_xor(sw, 16); qw += __shfl_xor(qw, 32);
        if (lane < 16) {  // combine the 4 waves via LDS atomics
            atomicAdd(&ssum[co + 0], rx); atomicAdd(&ssum[co + 1], ry);
            atomicAdd(&ssum[co + 2], rz); atomicAdd(&ssum[co + 3], rw2);
            atomicAdd(&ssq[co + 0], qx);  atomicAdd(&ssq[co + 1], qy);
            atomicAdd(&ssq[co + 2], qz);  atomicAdd(&ssq[co + 3], qw);
        }
        __syncthreads();
        if (t < 64) {
            float* p = statPart + (size_t)blockIdx.x * 128;
            p[t] = ssum[t];
            p[64 + t] = ssq[t];
        }
    }
}

// ---------------- reduce stats partials: [8192][128] -> stats[128] ----------
__global__ __launch_bounds__(256) void k_red(const float* __restrict__ part,
                                             float* __restrict__ stats) {
    __shared__ float sred[256];
    int t = threadIdx.x;
    int half = t >> 7;   // 0/1: which row of the pair
    int s = t & 127;     // stat id
    int r0 = blockIdx.x * 64;
    float acc = 0.0f;
#pragma unroll 4
    for (int k = 0; k < 32; ++k) {
        acc += part[(size_t)(r0 + k * 2 + half) * 128 + s];
    }
    sred[t] = acc;
    __syncthreads();
    if (t < 128) atomicAdd(&stats[t], sred[t] + sred[t + 128]);
}

// ---------------- BN scale/shift per channel --------------------------------
__global__ void k_bnfin(const float* __restrict__ stats, const float* __restrict__ gamma,
                        const float* __restrict__ beta, float* __restrict__ sc,
                        float* __restrict__ sh) {
    int f = threadIdx.x;
    if (f < 64) {
        float inv = 1.0f / (float)BN_;
        float mean = stats[f] * inv;
        float var  = stats[64 + f] * inv - mean * mean;
        float s = gamma[f] * rsqrtf(var + EPS_);
        sc[f] = s;
        sh[f] = beta[f] - mean * s;
    }
}

// ---------------- fused BN-apply + final linear -----------------------------
// 1024 blocks x 1024-elem chunks. Wave wv owns batches {2wv, 2wv+1} and scans
// the FULL chunk itself (i = base + k*64 + lane): 20 acc/thread, no spill.
// (R9 bug: i = base + k*256 + t gave each wave only 1/4 of the elements.)
__global__ __launch_bounds__(256) void k_final(
        const float* __restrict__ h, const float* __restrict__ linW,
        const float* __restrict__ linb, const float* __restrict__ sc,
        const float* __restrict__ sh, float* __restrict__ out) {
    int t = threadIdx.x;
    int lane = t & 63;
    int wv = t >> 6;
    int b0 = wv * 2, b1 = wv * 2 + 1;
    int base = blockIdx.x * (NF_ / 1024);  // 1024 per block
    int f = lane;                          // (i & 63) == lane: strides are x64
    float s = sc[f], shv = sh[f];
    float acc[C_][2];
#pragma unroll
    for (int c = 0; c < C_; ++c) { acc[c][0] = 0.0f; acc[c][1] = 0.0f; }

#pragma unroll 4
    for (int k = 0; k < 16; ++k) {
        int i = base + k * 64 + lane;
        float h0 = fmaf(h[(size_t)b0 * NF_ + i], s, shv);
        float h1 = fmaf(h[(size_t)b1 * NF_ + i], s, shv);
#pragma unroll
        for (int c = 0; c < C_; ++c) {
            float w = linW[(size_t)c * NF_ + i];
            acc[c][0] = fmaf(h0, w, acc[c][0]);
            acc[c][1] = fmaf(h1, w, acc[c][1]);
        }
    }

#pragma unroll
    for (int c = 0; c < C_; ++c) {
#pragma unroll
        for (int j = 0; j < 2; ++j) {
            float v = acc[c][j];
            v += __shfl_down(v, 32);
            v += __shfl_down(v, 16);
            v += __shfl_down(v, 8);
            v += __shfl_down(v, 4);
            v += __shfl_down(v, 2);
            v += __shfl_down(v, 1);
            acc[c][j] = v;
        }
    }
    if (lane == 0) {
#pragma unroll
        for (int c = 0; c < C_; ++c) {
            float v0 = acc[c][0], v1 = acc[c][1];
            if (blockIdx.x == 0) { v0 += linb[c]; v1 += linb[c]; }
            atomicAdd(&out[b0 * C_ + c], v0);
            atomicAdd(&out[b1 * C_ + c], v1);
        }
    }
}

extern "C" void kernel_launch(void* const* d_in, const int* in_sizes, int n_in,
                              void* d_out, int out_size, void* d_ws, size_t ws_size,
                              hipStream_t stream) {
    const float* x        = (const float*)d_in[0];
    const int*   edge_src = (const int*)d_in[1];
    const int*   edge_dst = (const int*)d_in[2];
    const float* W1       = (const float*)d_in[3];
    const float* b1       = (const float*)d_in[4];
    const float* W2       = (const float*)d_in[5];
    const float* b2       = (const float*)d_in[6];
    const float* gamma    = (const float*)d_in[7];
    const float* beta     = (const float*)d_in[8];
    const float* linW     = (const float*)d_in[9];
    const float* linb     = (const float*)d_in[10];
    float* out = (float*)d_out;

    char* w = (char*)d_ws;
    float* degOr = (float*)w;           w += BN_ * 4;
    float* degIr = (float*)w;           w += BN_ * 4;
    int*   cntI  = (int*)w;             w += BN_ * 4;
    unsigned short* csr = (unsigned short*)w; w += (size_t)BN_ * CAP_ * 2;
    float* bufA  = (float*)w;           w += (size_t)BNF_ * 4;
    float* bufB  = (float*)w;           w += (size_t)BNF_ * 4;
    float* statPart = (float*)w;        w += (size_t)NBLK_ * 128 * 4;  // 4 MB
    float* stats = (float*)w;           w += 128 * 4;
    float* sc    = (float*)w;           w += 64 * 4;
    float* sh    = (float*)w;           w += 64 * 4;

    // Build scratch aliases bufA/bufB (dead before mm1 writes bufA):
    unsigned int* partO   = (unsigned int*)bufA;
    unsigned int* partI   = partO + (size_t)B_ * NCH_ * NW_;
    unsigned int* baseArr = (unsigned int*)bufB;

    hipMemsetAsync(stats, 0, 128 * sizeof(float), stream);
    hipMemsetAsync(out, 0, B_ * C_ * sizeof(float), stream);

    // CSR build + degrees: two-phase privatized, zero global atomics
    k_count<<<B_ * NCH_, 256, 0, stream>>>(edge_src, edge_dst, partO, partI);
    k_offsets<<<BN_ / 4 / 256, 256, 0, stream>>>(partO, partI, baseArr, degOr, degIr, cntI);
    k_fill<<<B_ * NCH_, 256, 0, stream>>>(edge_src, edge_dst, baseArr, csr);

    // conv1 = relu(degIr * A (degOr * x @ W1) + b1); post-scale degOr preps conv2
    k_mmd<true><<<BN_ / 16, 256, 0, stream>>>(x, W1, degOr, bufA);          // z1
    k_gat<true, false><<<NBLK_, 256, 0, stream>>>(cntI, csr, bufA, degIr, degOr, b1, bufB, nullptr);

    // conv2 = degIr * A (h1z @ W2) + b2, with fused BN-stats partials
    k_mmd<false><<<BN_ / 16, 256, 0, stream>>>(bufB, W2, nullptr, bufA);    // z2
    k_gat<false, true><<<NBLK_, 256, 0, stream>>>(cntI, csr, bufA, degIr, degOr, b2, bufB, statPart);

    // reduce stats + BN coeffs + fused BN/linear
    k_red<<<NBLK_ / 64, 256, 0, stream>>>(statPart, stats);
    k_bnfin<<<1, 64, 0, stream>>>(stats, gamma, beta, sc, sh);
    k_final<<<1024, 256, 0, stream>>>(bufB, linW, linb, sc, sh, out);
}

// Round 11
// 320.904 us; speedup vs baseline: 2.2615x; 2.2615x over previous
//
#include <hip/hip_runtime.h>

#define B_     8
#define N_     16384
#define F_     64
#define E_     262144
#define C_     10
#define NF_    (N_ * F_)        // 1048576
#define BN_    (B_ * N_)        // 131072
#define BNF_   (B_ * N_ * F_)   // 8388608
#define BE_    (B_ * E_)        // 2097152
#define CAP_   48               // padded CSR row capacity; P(Poisson(16) >= 48) ~ 6e-11
#define CHUNK_ 4096             // edges per build workgroup
#define NCH_   (E_ / CHUNK_)    // 64 chunks per batch
#define NW_    (N_ / 4)         // 4096 packed-u8 words per batch
#define NBLK_  (BN_ / 16)       // 8192 gather blocks (stats partials rows)
#define NFB_   1024             // k_final blocks
#define EPS_   1e-5f

// ---------------- Build phase A: per-chunk privatized counts ----------------
__global__ __launch_bounds__(256) void k_count(const int* __restrict__ src,
                                               const int* __restrict__ dst,
                                               unsigned int* __restrict__ partO,
                                               unsigned int* __restrict__ partI) {
    __shared__ unsigned int pO[NW_];  // 16 KB
    __shared__ unsigned int pI[NW_];  // 16 KB
    int t = threadIdx.x;
    int b = blockIdx.x & 7, c = blockIdx.x >> 3;
    for (int i = t; i < NW_; i += 256) { pO[i] = 0; pI[i] = 0; }
    __syncthreads();
    const int* sb = src + (size_t)b * E_ + (size_t)c * CHUNK_;
    const int* db = dst + (size_t)b * E_ + (size_t)c * CHUNK_;
    for (int i = t; i < CHUNK_; i += 256) {
        int s = sb[i], d = db[i];
        atomicAdd(&pO[s >> 2], 1u << ((s & 3) * 8));
        atomicAdd(&pI[d >> 2], 1u << ((d & 3) * 8));
    }
    __syncthreads();
    size_t base = (size_t)(b * NCH_ + c) * NW_;
    for (int i = t; i < NW_; i += 256) {
        partO[base + i] = pO[i];
        partI[base + i] = pI[i];
    }
}

// ---------------- Build phase B: packed prefix over chunks + degrees --------
__global__ __launch_bounds__(256) void k_offsets(const unsigned int* __restrict__ partO,
                                                 const unsigned int* __restrict__ partI,
                                                 unsigned int* __restrict__ baseArr,
                                                 float* __restrict__ degOr,
                                                 float* __restrict__ degIr,
                                                 int* __restrict__ cntI_g) {
    int gw = blockIdx.x * 256 + threadIdx.x;  // word id in [0, BN_/4)
    int b = gw >> 12;
    int rw = gw & 4095;
    unsigned int sumI = 0, sumO = 0;
    for (int c = 0; c < NCH_; ++c) {
        size_t idx = (size_t)(b * NCH_ + c) * NW_ + rw;
        unsigned int wI = partI[idx];
        baseArr[idx] = sumI;  // exclusive prefix, packed u8 lanes
        sumI += wI;
        sumO += partO[idx];
    }
    int row0 = gw * 4;
#pragma unroll
    for (int r = 0; r < 4; ++r) {
        unsigned int ci = (sumI >> (r * 8)) & 0xFFu;
        unsigned int co = (sumO >> (r * 8)) & 0xFFu;
        degIr[row0 + r] = rsqrtf(fmaxf((float)ci, 1.0f));
        degOr[row0 + r] = rsqrtf(fmaxf((float)co, 1.0f));
        cntI_g[row0 + r] = (int)ci;
    }
}

// ---------------- Build phase C: deterministic-offset CSR fill --------------
__global__ __launch_bounds__(256) void k_fill(const int* __restrict__ src,
                                              const int* __restrict__ dst,
                                              const unsigned int* __restrict__ baseArr,
                                              unsigned short* __restrict__ csr) {
    __shared__ unsigned int cur[NW_];  // 16 KB
    __shared__ unsigned int bw[NW_];   // 16 KB
    int t = threadIdx.x;
    int b = blockIdx.x & 7, c = blockIdx.x >> 3;
    size_t pbase = (size_t)(b * NCH_ + c) * NW_;
    for (int i = t; i < NW_; i += 256) { cur[i] = 0; bw[i] = baseArr[pbase + i]; }
    __syncthreads();
    const int* sb = src + (size_t)b * E_ + (size_t)c * CHUNK_;
    const int* db = dst + (size_t)b * E_ + (size_t)c * CHUNK_;
    unsigned short* cb = csr + (size_t)b * N_ * CAP_;
    for (int i = t; i < CHUNK_; i += 256) {
        int s = sb[i], d = db[i];
        unsigned int sh = (d & 3) * 8;
        unsigned int old = atomicAdd(&cur[d >> 2], 1u << sh);
        unsigned int pos = ((old >> sh) & 0xFFu) + ((bw[d >> 2] >> sh) & 0xFFu);
        if (pos < CAP_) cb[d * CAP_ + pos] = (unsigned short)s;
    }
}

// ---------------- Dense mm: out = (in @ W) [* rowScale] ---------------------
template <bool SCALE>
__global__ __launch_bounds__(256) void k_mmd(const float* __restrict__ in,
                                             const float* __restrict__ W,
                                             const float* __restrict__ rs,
                                             float* __restrict__ out) {
    __shared__ float Wl[4096];        // 16 KB
    __shared__ float4 rows[16][16];   // 4 KB  [row][kGroup]
    int t = threadIdx.x;
    int b = blockIdx.x & 7;
    int rowg = b * N_ + (blockIdx.x >> 3) * 16;  // global row base
    for (int i = t; i < 1024; i += 256) ((float4*)Wl)[i] = ((const float4*)W)[i];
    rows[t >> 4][t & 15] = ((const float4*)(in + (size_t)(rowg + (t >> 4)) * 64))[t & 15];
    __syncthreads();
    int f = t & 63;
    int wv = t >> 6;  // wave -> rows wv*4 .. wv*4+3
    float a0 = 0.0f, a1 = 0.0f, a2 = 0.0f, a3 = 0.0f;
#pragma unroll
    for (int kg = 0; kg < 16; ++kg) {
        float4 r0 = rows[wv * 4 + 0][kg];
        float4 r1 = rows[wv * 4 + 1][kg];
        float4 r2 = rows[wv * 4 + 2][kg];
        float4 r3 = rows[wv * 4 + 3][kg];
        float w0 = Wl[(kg * 4 + 0) * 64 + f];
        float w1 = Wl[(kg * 4 + 1) * 64 + f];
        float w2 = Wl[(kg * 4 + 2) * 64 + f];
        float w3 = Wl[(kg * 4 + 3) * 64 + f];
        a0 = fmaf(r0.x, w0, a0); a0 = fmaf(r0.y, w1, a0); a0 = fmaf(r0.z, w2, a0); a0 = fmaf(r0.w, w3, a0);
        a1 = fmaf(r1.x, w0, a1); a1 = fmaf(r1.y, w1, a1); a1 = fmaf(r1.z, w2, a1); a1 = fmaf(r1.w, w3, a1);
        a2 = fmaf(r2.x, w0, a2); a2 = fmaf(r2.y, w1, a2); a2 = fmaf(r2.z, w2, a2); a2 = fmaf(r2.w, w3, a2);
        a3 = fmaf(r3.x, w0, a3); a3 = fmaf(r3.y, w1, a3); a3 = fmaf(r3.z, w2, a3); a3 = fmaf(r3.w, w3, a3);
    }
    int r0i = rowg + wv * 4;
    if (SCALE) {
        a0 *= rs[r0i]; a1 *= rs[r0i + 1]; a2 *= rs[r0i + 2]; a3 *= rs[r0i + 3];
    }
    out[(size_t)(r0i + 0) * 64 + f] = a0;
    out[(size_t)(r0i + 1) * 64 + f] = a1;
    out[(size_t)(r0i + 2) * 64 + f] = a2;
    out[(size_t)(r0i + 3) * 64 + f] = a3;
}

// ---------------- Lean gather + epilogue [+ fused BN stats partials] --------
// 256 threads = 4 waves; wave handles 4 rows. Lane: r = lane>>4, c = lane&15.
// CONV1: out = relu(g*degIr + b1) * degOr     CONV2: out = g*degIr + b2
// STATS: per-block channel sum/sumsq -> partials[block][128] (coalesced).
template <bool CONV1, bool STATS>
__global__ __launch_bounds__(256, 8) void k_gat(
        const int* __restrict__ cnt, const unsigned short* __restrict__ csr,
        const float* __restrict__ z, const float* __restrict__ degIr,
        const float* __restrict__ degOr, const float* __restrict__ bias,
        float* __restrict__ out, float* __restrict__ statPart) {
    __shared__ float ssum[64], ssq[64];
    int t = threadIdx.x;
    if (STATS) {
        if (t < 64) { ssum[t] = 0.0f; ssq[t] = 0.0f; }
        __syncthreads();
    }
    int lane = t & 63;
    int wave = t >> 6;
    int c = lane & 15;
    int b = blockIdx.x & 7;  // XCD swizzle: batch slice L2-resident
    int row = (blockIdx.x >> 3) * 16 + wave * 4 + (lane >> 4);
    int wid = b * N_ + row;
    const float* zb = z + (size_t)b * NF_;
    int lb = lane & 48;
    int co = c * 4;

    int n = cnt[wid];
    if (n > CAP_) n = CAP_;
    size_t cb = (size_t)wid * CAP_;
    int e0 = csr[cb + c] & 0x3FFF;        // mask: entries >= n may be stale
    int e1 = csr[cb + 16 + c] & 0x3FFF;
    int e2 = csr[cb + 32 + c] & 0x3FFF;
    float dIr = degIr[wid];               // early loads overlap gather
    const float4 bv = ((const float4*)bias)[c];
    int m = n;  // wave-uniform max count across the 4 rows
    m = max(m, __shfl_xor(m, 16));
    m = max(m, __shfl_xor(m, 32));

    float ax = 0.0f, ay = 0.0f, az = 0.0f, aw = 0.0f;

#define HALF(EREG, KOFF, JBASE)                                                \
    {                                                                          \
        float4 v[8];                                                           \
        int rem = n - (KOFF);                                                  \
        _Pragma("unroll")                                                      \
        for (int jj = 0; jj < 8; ++jj) {                                       \
            int s = __shfl(EREG, lb + (JBASE) + jj);                           \
            v[jj] = make_float4(0.0f, 0.0f, 0.0f, 0.0f);                       \
            if (jj < rem) v[jj] = *(const float4*)(zb + s * 64 + co);          \
        }                                                                      \
        _Pragma("unroll")                                                      \
        for (int jj = 0; jj < 8; ++jj) {                                       \
            ax += v[jj].x; ay += v[jj].y; az += v[jj].z; aw += v[jj].w;        \
        }                                                                      \
    }

    HALF(e0, 0, 0)
    if (m > 8)  HALF(e0, 8, 8)
    if (m > 16) HALF(e1, 16, 0)
    if (m > 24) HALF(e1, 24, 8)
    if (m > 32) HALF(e2, 32, 0)
    if (m > 40) HALF(e2, 40, 8)
#undef HALF

    float ox, oy, oz, ow;
    if (CONV1) {
        float po = degOr[wid];
        ox = fmaxf(fmaf(ax, dIr, bv.x), 0.0f) * po;
        oy = fmaxf(fmaf(ay, dIr, bv.y), 0.0f) * po;
        oz = fmaxf(fmaf(az, dIr, bv.z), 0.0f) * po;
        ow = fmaxf(fmaf(aw, dIr, bv.w), 0.0f) * po;
    } else {
        ox = fmaf(ax, dIr, bv.x);
        oy = fmaf(ay, dIr, bv.y);
        oz = fmaf(az, dIr, bv.z);
        ow = fmaf(aw, dIr, bv.w);
    }
    float4 o; o.x = ox; o.y = oy; o.z = oz; o.w = ow;
    *(float4*)(out + (size_t)wid * 64 + co) = o;

    if (STATS) {
        float sx = ox * ox, sy = oy * oy, sz = oz * oz, sw = ow * ow;
        // sum over the wave's 4 rows (lanes l, l^16, l^32, l^48)
        float rx = ox + __shfl_xor(ox, 16); rx += __shfl_xor(rx, 32);
        float ry = oy + __shfl_xor(oy, 16); ry += __shfl_xor(ry, 32);
        float rz = oz + __shfl_xor(oz, 16); rz += __shfl_xor(rz, 32);
        float rw2 = ow + __shfl_xor(ow, 16); rw2 += __shfl_xor(rw2, 32);
        float qx = sx + __shfl_xor(sx, 16); qx += __shfl_xor(qx, 32);
        float qy = sy + __shfl_xor(sy, 16); qy += __shfl_xor(qy, 32);
        float qz = sz + __shfl_xor(sz, 16); qz += __shfl_xor(qz, 32);
        float qw = sw + __shfl_xor(sw, 16); qw += __shfl_xor(qw, 32);
        if (lane < 16) {  // combine the 4 waves via LDS atomics (cheap, local)
            atomicAdd(&ssum[co + 0], rx); atomicAdd(&ssum[co + 1], ry);
            atomicAdd(&ssum[co + 2], rz); atomicAdd(&ssum[co + 3], rw2);
            atomicAdd(&ssq[co + 0], qx);  atomicAdd(&ssq[co + 1], qy);
            atomicAdd(&ssq[co + 2], qz);  atomicAdd(&ssq[co + 3], qw);
        }
        __syncthreads();
        if (t < 64) {
            float* p = statPart + (size_t)blockIdx.x * 128;
            p[t] = ssum[t];
            p[64 + t] = ssq[t];
        }
    }
}

// ---------------- reduce stats partials: [8192][128] -> stats2[32][128] -----
// Plain stores only (R10 lesson: same-sector global atomics = ~5 ns serial).
__global__ __launch_bounds__(256) void k_red(const float* __restrict__ part,
                                             float* __restrict__ stats2) {
    __shared__ float sred[256];
    int t = threadIdx.x;
    int half = t >> 7;   // 0/1
    int s = t & 127;     // stat id
    int r0 = blockIdx.x * (NBLK_ / 32);  // 256 rows per block
    float acc = 0.0f;
    for (int k = 0; k < 128; ++k) {
        acc += part[(size_t)(r0 + k * 2 + half) * 128 + s];
    }
    sred[t] = acc;
    __syncthreads();
    if (t < 128) stats2[blockIdx.x * 128 + t] = sred[t] + sred[t + 128];
}

// ---------------- BN scale/shift per channel (sums the 32 partial rows) -----
__global__ void k_bnfin(const float* __restrict__ stats2, const float* __restrict__ gamma,
                        const float* __restrict__ beta, float* __restrict__ sc,
                        float* __restrict__ sh) {
    int f = threadIdx.x;
    if (f < 64) {
        float sum = 0.0f, sq = 0.0f;
        for (int j = 0; j < 32; ++j) {
            sum += stats2[j * 128 + f];
            sq  += stats2[j * 128 + 64 + f];
        }
        float inv = 1.0f / (float)BN_;
        float mean = sum * inv;
        float var  = sq * inv - mean * mean;
        float s = gamma[f] * rsqrtf(var + EPS_);
        sc[f] = s;
        sh[f] = beta[f] - mean * s;
    }
}

// ---------------- fused BN-apply + final linear: per-block partials ---------
// 1024 blocks x 1024-elem chunks. Wave wv owns batches {2wv, 2wv+1}, scans the
// full chunk (i = base + k*64 + lane). NO global atomics: lane0 writes the 20
// wave-level dot-partials to pf[block][b*10+c]; k_fsum reduces.
__global__ __launch_bounds__(256) void k_final(
        const float* __restrict__ h, const float* __restrict__ linW,
        const float* __restrict__ sc, const float* __restrict__ sh,
        float* __restrict__ pf) {
    int t = threadIdx.x;
    int lane = t & 63;
    int wv = t >> 6;
    int b0 = wv * 2, b1 = wv * 2 + 1;
    int base = blockIdx.x * (NF_ / NFB_);  // 1024 per block
    float s = sc[lane], shv = sh[lane];    // (i & 63) == lane: strides are x64
    float acc[C_][2];
#pragma unroll
    for (int c = 0; c < C_; ++c) { acc[c][0] = 0.0f; acc[c][1] = 0.0f; }

#pragma unroll 4
    for (int k = 0; k < 16; ++k) {
        int i = base + k * 64 + lane;
        float h0 = fmaf(h[(size_t)b0 * NF_ + i], s, shv);
        float h1 = fmaf(h[(size_t)b1 * NF_ + i], s, shv);
#pragma unroll
        for (int c = 0; c < C_; ++c) {
            float w = linW[(size_t)c * NF_ + i];
            acc[c][0] = fmaf(h0, w, acc[c][0]);
            acc[c][1] = fmaf(h1, w, acc[c][1]);
        }
    }

#pragma unroll
    for (int c = 0; c < C_; ++c) {
#pragma unroll
        for (int j = 0; j < 2; ++j) {
            float v = acc[c][j];
            v += __shfl_down(v, 32);
            v += __shfl_down(v, 16);
            v += __shfl_down(v, 8);
            v += __shfl_down(v, 4);
            v += __shfl_down(v, 2);
            v += __shfl_down(v, 1);
            acc[c][j] = v;
        }
    }
    if (lane == 0) {
        float* p = pf + (size_t)blockIdx.x * 80;
#pragma unroll
        for (int c = 0; c < C_; ++c) {
            p[b0 * C_ + c] = acc[c][0];
            p[b1 * C_ + c] = acc[c][1];
        }
    }
}

// ---------------- final sum: pf[1024][80] -> out[80] ------------------------
__global__ __launch_bounds__(64) void k_fsum(const float* __restrict__ pf,
                                             const float* __restrict__ linb,
                                             float* __restrict__ out) {
    int o = blockIdx.x;        // 0..79 = b*10+c
    int lane = threadIdx.x;
    float acc = 0.0f;
#pragma unroll
    for (int k = 0; k < 16; ++k) {
        acc += pf[(size_t)(k * 64 + lane) * 80 + o];
    }
    acc += __shfl_down(acc, 32);
    acc += __shfl_down(acc, 16);
    acc += __shfl_down(acc, 8);
    acc += __shfl_down(acc, 4);
    acc += __shfl_down(acc, 2);
    acc += __shfl_down(acc, 1);
    if (lane == 0) out[o] = acc + linb[o % C_];
}

extern "C" void kernel_launch(void* const* d_in, const int* in_sizes, int n_in,
                              void* d_out, int out_size, void* d_ws, size_t ws_size,
                              hipStream_t stream) {
    const float* x        = (const float*)d_in[0];
    const int*   edge_src = (const int*)d_in[1];
    const int*   edge_dst = (const int*)d_in[2];
    const float* W1       = (const float*)d_in[3];
    const float* b1       = (const float*)d_in[4];
    const float* W2       = (const float*)d_in[5];
    const float* b2       = (const float*)d_in[6];
    const float* gamma    = (const float*)d_in[7];
    const float* beta     = (const float*)d_in[8];
    const float* linW     = (const float*)d_in[9];
    const float* linb     = (const float*)d_in[10];
    float* out = (float*)d_out;

    char* w = (char*)d_ws;
    float* degOr = (float*)w;           w += BN_ * 4;
    float* degIr = (float*)w;           w += BN_ * 4;
    int*   cntI  = (int*)w;             w += BN_ * 4;
    unsigned short* csr = (unsigned short*)w; w += (size_t)BN_ * CAP_ * 2;
    float* bufA  = (float*)w;           w += (size_t)BNF_ * 4;
    float* bufB  = (float*)w;           w += (size_t)BNF_ * 4;
    float* statPart = (float*)w;        w += (size_t)NBLK_ * 128 * 4;  // 4 MB
    float* stats2 = (float*)w;          w += 32 * 128 * 4;
    float* pf    = (float*)w;           w += (size_t)NFB_ * 80 * 4;    // 320 KB
    float* sc    = (float*)w;           w += 64 * 4;
    float* sh    = (float*)w;           w += 64 * 4;

    // Build scratch aliases bufA/bufB (dead before mm1 writes bufA):
    unsigned int* partO   = (unsigned int*)bufA;
    unsigned int* partI   = partO + (size_t)B_ * NCH_ * NW_;
    unsigned int* baseArr = (unsigned int*)bufB;

    // CSR build + degrees: two-phase privatized, zero global atomics
    k_count<<<B_ * NCH_, 256, 0, stream>>>(edge_src, edge_dst, partO, partI);
    k_offsets<<<BN_ / 4 / 256, 256, 0, stream>>>(partO, partI, baseArr, degOr, degIr, cntI);
    k_fill<<<B_ * NCH_, 256, 0, stream>>>(edge_src, edge_dst, baseArr, csr);

    // conv1 = relu(degIr * A (degOr * x @ W1) + b1); post-scale degOr preps conv2
    k_mmd<true><<<BN_ / 16, 256, 0, stream>>>(x, W1, degOr, bufA);          // z1
    k_gat<true, false><<<NBLK_, 256, 0, stream>>>(cntI, csr, bufA, degIr, degOr, b1, bufB, nullptr);

    // conv2 = degIr * A (h1z @ W2) + b2, with fused BN-stats partials
    k_mmd<false><<<BN_ / 16, 256, 0, stream>>>(bufB, W2, nullptr, bufA);    // z2
    k_gat<false, true><<<NBLK_, 256, 0, stream>>>(cntI, csr, bufA, degIr, degOr, b2, bufB, statPart);

    // stats reduce (plain stores) + BN coeffs + BN/linear partials + final sum
    k_red<<<32, 256, 0, stream>>>(statPart, stats2);
    k_bnfin<<<1, 64, 0, stream>>>(stats2, gamma, beta, sc, sh);
    k_final<<<NFB_, 256, 0, stream>>>(bufB, linW, sc, sh, pf);
    k_fsum<<<80, 64, 0, stream>>>(pf, linb, out);
}

// Round 12
// 283.428 us; speedup vs baseline: 2.5605x; 1.1322x over previous
//
#include <hip/hip_runtime.h>

#define B_     8
#define N_     16384
#define F_     64
#define E_     262144
#define C_     10
#define NF_    (N_ * F_)        // 1048576
#define BN_    (B_ * N_)        // 131072
#define BNF_   (B_ * N_ * F_)   // 8388608
#define BE_    (B_ * E_)        // 2097152
#define CAP_   48               // padded CSR row capacity; P(Poisson(16) >= 48) ~ 6e-11
#define CHUNK_ 4096             // edges per build workgroup
#define NCH_   (E_ / CHUNK_)    // 64 chunks per batch
#define NW_    (N_ / 4)         // 4096 packed-u8 words per batch
#define NSB_   2048             // k_stats2 blocks
#define NFB_   1024             // k_final blocks
#define EPS_   1e-5f

typedef _Float16 h8 __attribute__((ext_vector_type(8)));
typedef _Float16 h4 __attribute__((ext_vector_type(4)));

// ---------------- Build phase A: per-chunk privatized counts ----------------
__global__ __launch_bounds__(256) void k_count(const int* __restrict__ src,
                                               const int* __restrict__ dst,
                                               unsigned int* __restrict__ partO,
                                               unsigned int* __restrict__ partI) {
    __shared__ unsigned int pO[NW_];  // 16 KB
    __shared__ unsigned int pI[NW_];  // 16 KB
    int t = threadIdx.x;
    int b = blockIdx.x & 7, c = blockIdx.x >> 3;
    for (int i = t; i < NW_; i += 256) { pO[i] = 0; pI[i] = 0; }
    __syncthreads();
    const int* sb = src + (size_t)b * E_ + (size_t)c * CHUNK_;
    const int* db = dst + (size_t)b * E_ + (size_t)c * CHUNK_;
    for (int i = t; i < CHUNK_; i += 256) {
        int s = sb[i], d = db[i];
        atomicAdd(&pO[s >> 2], 1u << ((s & 3) * 8));
        atomicAdd(&pI[d >> 2], 1u << ((d & 3) * 8));
    }
    __syncthreads();
    size_t base = (size_t)(b * NCH_ + c) * NW_;
    for (int i = t; i < NW_; i += 256) {
        partO[base + i] = pO[i];
        partI[base + i] = pI[i];
    }
}

// ---------------- Build phase B: packed prefix over chunks + degrees --------
__global__ __launch_bounds__(256) void k_offsets(const unsigned int* __restrict__ partO,
                                                 const unsigned int* __restrict__ partI,
                                                 unsigned int* __restrict__ baseArr,
                                                 float* __restrict__ degOr,
                                                 float* __restrict__ degIr,
                                                 int* __restrict__ cntI_g) {
    int gw = blockIdx.x * 256 + threadIdx.x;  // word id in [0, BN_/4)
    int b = gw >> 12;
    int rw = gw & 4095;
    unsigned int sumI = 0, sumO = 0;
    for (int c = 0; c < NCH_; ++c) {
        size_t idx = (size_t)(b * NCH_ + c) * NW_ + rw;
        unsigned int wI = partI[idx];
        baseArr[idx] = sumI;  // exclusive prefix, packed u8 lanes
        sumI += wI;
        sumO += partO[idx];
    }
    int row0 = gw * 4;
#pragma unroll
    for (int r = 0; r < 4; ++r) {
        unsigned int ci = (sumI >> (r * 8)) & 0xFFu;
        unsigned int co = (sumO >> (r * 8)) & 0xFFu;
        degIr[row0 + r] = rsqrtf(fmaxf((float)ci, 1.0f));
        degOr[row0 + r] = rsqrtf(fmaxf((float)co, 1.0f));
        cntI_g[row0 + r] = (int)ci;
    }
}

// ---------------- Build phase C: deterministic-offset CSR fill --------------
__global__ __launch_bounds__(256) void k_fill(const int* __restrict__ src,
                                              const int* __restrict__ dst,
                                              const unsigned int* __restrict__ baseArr,
                                              unsigned short* __restrict__ csr) {
    __shared__ unsigned int cur[NW_];  // 16 KB
    __shared__ unsigned int bw[NW_];   // 16 KB
    int t = threadIdx.x;
    int b = blockIdx.x & 7, c = blockIdx.x >> 3;
    size_t pbase = (size_t)(b * NCH_ + c) * NW_;
    for (int i = t; i < NW_; i += 256) { cur[i] = 0; bw[i] = baseArr[pbase + i]; }
    __syncthreads();
    const int* sb = src + (size_t)b * E_ + (size_t)c * CHUNK_;
    const int* db = dst + (size_t)b * E_ + (size_t)c * CHUNK_;
    unsigned short* cb = csr + (size_t)b * N_ * CAP_;
    for (int i = t; i < CHUNK_; i += 256) {
        int s = sb[i], d = db[i];
        unsigned int sh = (d & 3) * 8;
        unsigned int old = atomicAdd(&cur[d >> 2], 1u << sh);
        unsigned int pos = ((old >> sh) & 0xFFu) + ((bw[d >> 2] >> sh) & 0xFFu);
        if (pos < CAP_) cb[d * CAP_ + pos] = (unsigned short)s;
    }
}

// ---------------- Dense mm: out = (in @ W) [* rowScale], fp16 in/out opts ---
template <bool SCALE, bool IN16, bool OUT16>
__global__ __launch_bounds__(256) void k_mmd(const float* __restrict__ in32,
                                             const _Float16* __restrict__ in16,
                                             const float* __restrict__ W,
                                             const float* __restrict__ rs,
                                             float* __restrict__ out32,
                                             _Float16* __restrict__ out16) {
    __shared__ float Wl[4096];        // 16 KB
    __shared__ float4 rows[16][16];   // 4 KB  [row][kGroup]
    int t = threadIdx.x;
    int b = blockIdx.x & 7;
    int rowg = b * N_ + (blockIdx.x >> 3) * 16;  // global row base
    for (int i = t; i < 1024; i += 256) ((float4*)Wl)[i] = ((const float4*)W)[i];
    {
        int rr = t >> 4, g = t & 15;
        if (IN16) {
            h4 hv = *(const h4*)(in16 + (size_t)(rowg + rr) * 64 + g * 4);
            rows[rr][g] = make_float4((float)hv[0], (float)hv[1], (float)hv[2], (float)hv[3]);
        } else {
            rows[rr][g] = ((const float4*)(in32 + (size_t)(rowg + rr) * 64))[g];
        }
    }
    __syncthreads();
    int f = t & 63;
    int wv = t >> 6;  // wave -> rows wv*4 .. wv*4+3
    float a0 = 0.0f, a1 = 0.0f, a2 = 0.0f, a3 = 0.0f;
#pragma unroll
    for (int kg = 0; kg < 16; ++kg) {
        float4 r0 = rows[wv * 4 + 0][kg];
        float4 r1 = rows[wv * 4 + 1][kg];
        float4 r2 = rows[wv * 4 + 2][kg];
        float4 r3 = rows[wv * 4 + 3][kg];
        float w0 = Wl[(kg * 4 + 0) * 64 + f];
        float w1 = Wl[(kg * 4 + 1) * 64 + f];
        float w2 = Wl[(kg * 4 + 2) * 64 + f];
        float w3 = Wl[(kg * 4 + 3) * 64 + f];
        a0 = fmaf(r0.x, w0, a0); a0 = fmaf(r0.y, w1, a0); a0 = fmaf(r0.z, w2, a0); a0 = fmaf(r0.w, w3, a0);
        a1 = fmaf(r1.x, w0, a1); a1 = fmaf(r1.y, w1, a1); a1 = fmaf(r1.z, w2, a1); a1 = fmaf(r1.w, w3, a1);
        a2 = fmaf(r2.x, w0, a2); a2 = fmaf(r2.y, w1, a2); a2 = fmaf(r2.z, w2, a2); a2 = fmaf(r2.w, w3, a2);
        a3 = fmaf(r3.x, w0, a3); a3 = fmaf(r3.y, w1, a3); a3 = fmaf(r3.z, w2, a3); a3 = fmaf(r3.w, w3, a3);
    }
    int r0i = rowg + wv * 4;
    if (SCALE) {
        a0 *= rs[r0i]; a1 *= rs[r0i + 1]; a2 *= rs[r0i + 2]; a3 *= rs[r0i + 3];
    }
    if (OUT16) {
        out16[(size_t)(r0i + 0) * 64 + f] = (_Float16)a0;
        out16[(size_t)(r0i + 1) * 64 + f] = (_Float16)a1;
        out16[(size_t)(r0i + 2) * 64 + f] = (_Float16)a2;
        out16[(size_t)(r0i + 3) * 64 + f] = (_Float16)a3;
    } else {
        out32[(size_t)(r0i + 0) * 64 + f] = a0;
        out32[(size_t)(r0i + 1) * 64 + f] = a1;
        out32[(size_t)(r0i + 2) * 64 + f] = a2;
        out32[(size_t)(r0i + 3) * 64 + f] = a3;
    }
}

// ---------------- Lean gather, fp16 z: 8 edges per dwordx4 load -------------
// 256 threads = 4 waves; wave = 8 subgroups of 8 lanes; wave handles 8 rows.
// Lane: r = lane>>3, c8 = lane&7 (8 halves = 16 B). One load instr = 8 edges.
// Per 8-edge segment: fp16 pairwise-tree sum (pk adds), fp32 across segments.
// CONV1: out16 = relu(g*degIr + b1) * degOr     CONV2: out32 = g*degIr + b2
template <bool CONV1>
__global__ __launch_bounds__(256, 6) void k_gat(
        const int* __restrict__ cnt, const unsigned short* __restrict__ csr,
        const _Float16* __restrict__ z, const float* __restrict__ degIr,
        const float* __restrict__ degOr, const float* __restrict__ bias,
        _Float16* __restrict__ out16, float* __restrict__ out32) {
    int t = threadIdx.x;
    int lane = t & 63;
    int wave = t >> 6;
    int c8 = lane & 7;
    int b = blockIdx.x & 7;  // XCD swizzle: batch slice L2-resident
    int row = (blockIdx.x >> 3) * 32 + wave * 8 + (lane >> 3);
    int wid = b * N_ + row;
    const _Float16* zb = z + (size_t)b * NF_;
    int lb = lane & 56;
    int ho = c8 * 8;  // half offset within row

    int n = cnt[wid];
    if (n > CAP_) n = CAP_;
    size_t cb = (size_t)wid * CAP_;
    int e0 = csr[cb + c8] & 0x3FFF;       // stale entries masked to valid range
    int e1 = csr[cb + 8 + c8] & 0x3FFF;
    int e2 = csr[cb + 16 + c8] & 0x3FFF;
    int e3 = csr[cb + 24 + c8] & 0x3FFF;
    int e4 = csr[cb + 32 + c8] & 0x3FFF;
    int e5 = csr[cb + 40 + c8] & 0x3FFF;
    float dIr = degIr[wid];
    float4 bv0 = *(const float4*)(bias + ho);
    float4 bv1 = *(const float4*)(bias + ho + 4);
    int m = n;  // wave-uniform max count across the 8 rows
    m = max(m, __shfl_xor(m, 8));
    m = max(m, __shfl_xor(m, 16));
    m = max(m, __shfl_xor(m, 32));

    float af[8];
#pragma unroll
    for (int i = 0; i < 8; ++i) af[i] = 0.0f;

#define SEG(EREG, KOFF)                                                        \
    {                                                                          \
        int rem = n - (KOFF);                                                  \
        h8 v[8];                                                               \
        _Pragma("unroll")                                                      \
        for (int jj = 0; jj < 8; ++jj) {                                       \
            int s = __shfl(EREG, lb + jj);                                     \
            h8 vv = {};                                                        \
            if (jj < rem) vv = *(const h8*)(zb + s * 64 + ho);                 \
            v[jj] = vv;                                                        \
        }                                                                      \
        h8 s0 = v[0] + v[1], s1 = v[2] + v[3];                                 \
        h8 s2 = v[4] + v[5], s3 = v[6] + v[7];                                 \
        h8 s4 = s0 + s1, s5 = s2 + s3;                                         \
        h8 s6 = s4 + s5;                                                       \
        _Pragma("unroll")                                                      \
        for (int i = 0; i < 8; ++i) af[i] += (float)s6[i];                     \
    }

    SEG(e0, 0)
    if (m > 8)  SEG(e1, 8)
    if (m > 16) SEG(e2, 16)
    if (m > 24) SEG(e3, 24)
    if (m > 32) SEG(e4, 32)
    if (m > 40) SEG(e5, 40)
#undef SEG

    float bb[8] = {bv0.x, bv0.y, bv0.z, bv0.w, bv1.x, bv1.y, bv1.z, bv1.w};
    if (CONV1) {
        float po = degOr[wid];
        h8 ov;
#pragma unroll
        for (int i = 0; i < 8; ++i) {
            ov[i] = (_Float16)(fmaxf(fmaf(af[i], dIr, bb[i]), 0.0f) * po);
        }
        *(h8*)(out16 + (size_t)wid * 64 + ho) = ov;
    } else {
        float4 o0, o1;
        o0.x = fmaf(af[0], dIr, bb[0]); o0.y = fmaf(af[1], dIr, bb[1]);
        o0.z = fmaf(af[2], dIr, bb[2]); o0.w = fmaf(af[3], dIr, bb[3]);
        o1.x = fmaf(af[4], dIr, bb[4]); o1.y = fmaf(af[5], dIr, bb[5]);
        o1.z = fmaf(af[6], dIr, bb[6]); o1.w = fmaf(af[7], dIr, bb[7]);
        float* op = out32 + (size_t)wid * 64 + ho;
        *(float4*)op = o0;
        *(float4*)(op + 4) = o1;
    }
}

// ---------------- BN stats partials: h2 -> part[2048][128] (plain stores) ---
__global__ __launch_bounds__(256) void k_stats2(const float* __restrict__ h,
                                                float* __restrict__ part) {
    int t = threadIdx.x;
    int base = blockIdx.x * (BNF_ / NSB_);  // 4096 per block
    float s = 0.0f, q = 0.0f;
#pragma unroll 4
    for (int k = 0; k < 16; ++k) {
        float v = h[(size_t)base + k * 256 + t];
        s += v;
        q += v * v;
    }
    __shared__ float ls[256], lq[256];
    ls[t] = s;
    lq[t] = q;
    __syncthreads();
    if (t < 64) {  // channel f = t (base, strides are x64 multiples)
        s = ls[t] + ls[t + 64] + ls[t + 128] + ls[t + 192];
        q = lq[t] + lq[t + 64] + lq[t + 128] + lq[t + 192];
        float* p = part + (size_t)blockIdx.x * 128;
        p[t] = s;
        p[64 + t] = q;
    }
}

// ---------------- reduce stats partials: [2048][128] -> stats2[32][128] -----
__global__ __launch_bounds__(256) void k_red(const float* __restrict__ part,
                                             float* __restrict__ stats2) {
    __shared__ float sred[256];
    int t = threadIdx.x;
    int half = t >> 7;   // 0/1
    int s = t & 127;     // stat id
    int r0 = blockIdx.x * (NSB_ / 32);  // 64 rows per block
    float acc = 0.0f;
    for (int k = 0; k < NSB_ / 32 / 2; ++k) {
        acc += part[(size_t)(r0 + k * 2 + half) * 128 + s];
    }
    sred[t] = acc;
    __syncthreads();
    if (t < 128) stats2[blockIdx.x * 128 + t] = sred[t] + sred[t + 128];
}

// ---------------- BN scale/shift per channel (sums the 32 partial rows) -----
__global__ void k_bnfin(const float* __restrict__ stats2, const float* __restrict__ gamma,
                        const float* __restrict__ beta, float* __restrict__ sc,
                        float* __restrict__ sh) {
    int f = threadIdx.x;
    if (f < 64) {
        float sum = 0.0f, sq = 0.0f;
        for (int j = 0; j < 32; ++j) {
            sum += stats2[j * 128 + f];
            sq  += stats2[j * 128 + 64 + f];
        }
        float inv = 1.0f / (float)BN_;
        float mean = sum * inv;
        float var  = sq * inv - mean * mean;
        float s = gamma[f] * rsqrtf(var + EPS_);
        sc[f] = s;
        sh[f] = beta[f] - mean * s;
    }
}

// ---------------- fused BN-apply + final linear: per-block partials ---------
__global__ __launch_bounds__(256) void k_final(
        const float* __restrict__ h, const float* __restrict__ linW,
        const float* __restrict__ sc, const float* __restrict__ sh,
        float* __restrict__ pf) {
    int t = threadIdx.x;
    int lane = t & 63;
    int wv = t >> 6;
    int b0 = wv * 2, b1 = wv * 2 + 1;
    int base = blockIdx.x * (NF_ / NFB_);  // 1024 per block
    float s = sc[lane], shv = sh[lane];    // (i & 63) == lane: strides are x64
    float acc[C_][2];
#pragma unroll
    for (int c = 0; c < C_; ++c) { acc[c][0] = 0.0f; acc[c][1] = 0.0f; }

#pragma unroll 4
    for (int k = 0; k < 16; ++k) {
        int i = base + k * 64 + lane;
        float h0 = fmaf(h[(size_t)b0 * NF_ + i], s, shv);
        float h1 = fmaf(h[(size_t)b1 * NF_ + i], s, shv);
#pragma unroll
        for (int c = 0; c < C_; ++c) {
            float w = linW[(size_t)c * NF_ + i];
            acc[c][0] = fmaf(h0, w, acc[c][0]);
            acc[c][1] = fmaf(h1, w, acc[c][1]);
        }
    }

#pragma unroll
    for (int c = 0; c < C_; ++c) {
#pragma unroll
        for (int j = 0; j < 2; ++j) {
            float v = acc[c][j];
            v += __shfl_down(v, 32);
            v += __shfl_down(v, 16);
            v += __shfl_down(v, 8);
            v += __shfl_down(v, 4);
            v += __shfl_down(v, 2);
            v += __shfl_down(v, 1);
            acc[c][j] = v;
        }
    }
    if (lane == 0) {
        float* p = pf + (size_t)blockIdx.x * 80;
#pragma unroll
        for (int c = 0; c < C_; ++c) {
            p[b0 * C_ + c] = acc[c][0];
            p[b1 * C_ + c] = acc[c][1];
        }
    }
}

// ---------------- final sum: pf[1024][80] -> out[80] ------------------------
__global__ __launch_bounds__(64) void k_fsum(const float* __restrict__ pf,
                                             const float* __restrict__ linb,
                                             float* __restrict__ out) {
    int o = blockIdx.x;        // 0..79 = b*10+c
    int lane = threadIdx.x;
    float acc = 0.0f;
#pragma unroll
    for (int k = 0; k < 16; ++k) {
        acc += pf[(size_t)(k * 64 + lane) * 80 + o];
    }
    acc += __shfl_down(acc, 32);
    acc += __shfl_down(acc, 16);
    acc += __shfl_down(acc, 8);
    acc += __shfl_down(acc, 4);
    acc += __shfl_down(acc, 2);
    acc += __shfl_down(acc, 1);
    if (lane == 0) out[o] = acc + linb[o % C_];
}

extern "C" void kernel_launch(void* const* d_in, const int* in_sizes, int n_in,
                              void* d_out, int out_size, void* d_ws, size_t ws_size,
                              hipStream_t stream) {
    const float* x        = (const float*)d_in[0];
    const int*   edge_src = (const int*)d_in[1];
    const int*   edge_dst = (const int*)d_in[2];
    const float* W1       = (const float*)d_in[3];
    const float* b1       = (const float*)d_in[4];
    const float* W2       = (const float*)d_in[5];
    const float* b2       = (const float*)d_in[6];
    const float* gamma    = (const float*)d_in[7];
    const float* beta     = (const float*)d_in[8];
    const float* linW     = (const float*)d_in[9];
    const float* linb     = (const float*)d_in[10];
    float* out = (float*)d_out;

    char* w = (char*)d_ws;
    float* degOr = (float*)w;           w += BN_ * 4;
    float* degIr = (float*)w;           w += BN_ * 4;
    int*   cntI  = (int*)w;             w += BN_ * 4;
    unsigned short* csr = (unsigned short*)w; w += (size_t)BN_ * CAP_ * 2;
    _Float16* z    = (_Float16*)w;      w += (size_t)BNF_ * 2;  // z1 then z2
    _Float16* h1z  = (_Float16*)w;      w += (size_t)BNF_ * 2;
    float* h2    = (float*)w;           w += (size_t)BNF_ * 4;
    float* statPart = (float*)w;        w += (size_t)NSB_ * 128 * 4;
    float* stats2 = (float*)w;          w += 32 * 128 * 4;
    float* pf    = (float*)w;           w += (size_t)NFB_ * 80 * 4;
    float* sc    = (float*)w;           w += 64 * 4;
    float* sh    = (float*)w;           w += 64 * 4;

    // Build scratch aliases (dead before the aliased buffers are written):
    unsigned int* partO   = (unsigned int*)h2;                  // 8 MB
    unsigned int* partI   = partO + (size_t)B_ * NCH_ * NW_;    // 8 MB
    unsigned int* baseArr = (unsigned int*)z;                   // 8 MB

    // CSR build + degrees: two-phase privatized, zero global atomics
    k_count<<<B_ * NCH_, 256, 0, stream>>>(edge_src, edge_dst, partO, partI);
    k_offsets<<<BN_ / 4 / 256, 256, 0, stream>>>(partO, partI, baseArr, degOr, degIr, cntI);
    k_fill<<<B_ * NCH_, 256, 0, stream>>>(edge_src, edge_dst, baseArr, csr);

    // conv1 = relu(degIr * A (degOr * x @ W1) + b1), post-scale degOr
    k_mmd<true, false, true><<<BN_ / 16, 256, 0, stream>>>(x, nullptr, W1, degOr, nullptr, z);
    k_gat<true><<<BN_ / 32, 256, 0, stream>>>(cntI, csr, z, degIr, degOr, b1, h1z, nullptr);

    // conv2 = degIr * A (h1z @ W2) + b2
    k_mmd<false, true, true><<<BN_ / 16, 256, 0, stream>>>(nullptr, h1z, W2, nullptr, nullptr, z);
    k_gat<false><<<BN_ / 32, 256, 0, stream>>>(cntI, csr, z, degIr, nullptr, b2, nullptr, h2);

    // BN stats (plain-store partials) + coeffs + fused BN/linear + final sum
    k_stats2<<<NSB_, 256, 0, stream>>>(h2, statPart);
    k_red<<<32, 256, 0, stream>>>(statPart, stats2);
    k_bnfin<<<1, 64, 0, stream>>>(stats2, gamma, beta, sc, sh);
    k_final<<<NFB_, 256, 0, stream>>>(h2, linW, sc, sh, pf);
    k_fsum<<<80, 64, 0, stream>>>(pf, linb, out);
}